// Round 18
// baseline (413.702 us; speedup 1.0000x reference)
//
#include <hip/hip_runtime.h>
#include <hip/hip_bf16.h>

#define HD 128
#define NGAUSS 50
#define NLAYER 6
#define NGRAPH 16
#define NCLS 97
#define NTAB2 4096
#define WMAX 12.0f

typedef __attribute__((ext_vector_type(8))) short bf16x8;
typedef __attribute__((ext_vector_type(4))) float f32x4;
typedef __attribute__((ext_vector_type(8))) ushort u16x8;
typedef __attribute__((ext_vector_type(4))) ushort u16x4;

__device__ __forceinline__ float ssp_f(float x) {
    float e = __expf(-fabsf(x));
    return fmaxf(x, 0.0f) + __logf(0.5f + 0.5f * e);
}
__device__ __forceinline__ ushort f2bf(float f) {   // RNE f32->bf16
    uint u = __float_as_uint(f);
    return (ushort)((u + 0x7FFFu + ((u >> 16) & 1u)) >> 16);
}
__device__ __forceinline__ float bf2f(ushort s) {
    return __uint_as_float(((uint)s) << 16);
}

// ================= CSR build =================
__global__ void hist_kernel(const int* __restrict__ col, int* __restrict__ deg, int E) {
    int e = blockIdx.x * blockDim.x + threadIdx.x;
    if (e < E) atomicAdd(&deg[col[e]], 1);
}

__global__ void scan1_kernel(const int* __restrict__ deg, int* __restrict__ rowp,
                             int* __restrict__ bsum, int N) {
    __shared__ int sm[256];
    const int t = threadIdx.x, i = blockIdx.x * 256 + t;
    int v = (i < N) ? deg[i] : 0;
    sm[t] = v;
    __syncthreads();
    for (int off = 1; off < 256; off <<= 1) {
        int x = sm[t];
        int a = (t >= off) ? sm[t - off] : 0;
        __syncthreads();
        sm[t] = x + a;
        __syncthreads();
    }
    if (i < N) rowp[i] = sm[t] - v;
    if (t == 255) bsum[blockIdx.x] = sm[255];
}
__global__ void scan2_kernel(const int* __restrict__ bsum, int* __restrict__ boff,
                             int NB, int* __restrict__ rowpN) {
    __shared__ int sm[256];
    const int t = threadIdx.x;
    int v = (t < NB) ? bsum[t] : 0;
    sm[t] = v;
    __syncthreads();
    for (int off = 1; off < 256; off <<= 1) {
        int x = sm[t];
        int a = (t >= off) ? sm[t - off] : 0;
        __syncthreads();
        sm[t] = x + a;
        __syncthreads();
    }
    if (t < NB) boff[t] = sm[t] - v;
    if (t == 255) *rowpN = sm[255];
}
__global__ void scan3_kernel(int* __restrict__ rowp, const int* __restrict__ boff,
                             int* __restrict__ cursor, int N) {
    int i = blockIdx.x * blockDim.x + threadIdx.x;
    if (i < N) {
        int r = rowp[i] + boff[i >> 8];
        rowp[i] = r;
        cursor[i] = r;
    }
}

// per-slot metadata (4 B): row | (nearest_tab_idx << 16). cenv folded into table.
__global__ void fill_kernel(const int* __restrict__ row, const int* __restrict__ col,
                            const float* __restrict__ pos, int* __restrict__ cursor,
                            uint* __restrict__ meta, int E) {
    int e = blockIdx.x * blockDim.x + threadIdx.x;
    if (e >= E) return;
    int c = col[e], r = row[e];
    int slot = atomicAdd(&cursor[c], 1);
    float dx = pos[r*3+0] - pos[c*3+0];
    float dy = pos[r*3+1] - pos[c*3+1];
    float dz = pos[r*3+2] - pos[c*3+2];
    float w = sqrtf(dx*dx + dy*dy + dz*dz);
    const float invDW = (float)(NTAB2 - 1) / WMAX;
    int i = (int)(w * invDW + 0.5f);     // nearest neighbor
    i = min(i, NTAB2 - 1);
    meta[slot] = ((uint)r) | (((uint)i) << 16);
}

// ================= weight prep =================
__global__ void prep_kernel(const float* __restrict__ m1w, const float* __restrict__ c1w,
                            const float* __restrict__ c2w, const float* __restrict__ lw,
                            const float* __restrict__ l1w, const float* __restrict__ m2w,
                            ushort* __restrict__ m1T, ushort* __restrict__ nodeThi,
                            ushort* __restrict__ nodeTlo, ushort* __restrict__ m2T) {
    int idx = blockIdx.x * blockDim.x + threadIdx.x;
    const int S1 = 6*128*64, S2 = 19*128*128, S3 = 6*128*128;
    if (idx < S1) {
        int l = idx / 8192, r = idx % 8192, c = r / 64, k = r % 64;
        float v = (k < NGAUSS) ? m1w[(size_t)l*NGAUSS*128 + k*128 + c] : 0.0f;
        m1T[(size_t)l*8192 + c*64 + k] = f2bf(v);
    } else if (idx < S1 + S2) {
        int j = idx - S1;
        int m = j / 16384, r = j % 16384, c = r / 128, k = r % 128;
        const float* src;
        if (m < 6)       src = c1w + (size_t)m*16384;
        else if (m < 12) src = c2w + (size_t)(m-6)*16384;
        else if (m < 18) src = lw  + (size_t)(m-12)*16384;
        else             src = l1w;
        float v = src[k*128 + c];
        ushort hi = f2bf(v);
        nodeThi[(size_t)m*16384 + c*128 + k] = hi;
        nodeTlo[(size_t)m*16384 + c*128 + k] = f2bf(v - bf2f(hi));
    } else if (idx < S1 + S2 + S3) {
        int j = idx - S1 - S2;
        int l = j / 16384, r = j % 16384, c = r / 128, k = r % 128;
        m2T[(size_t)l*16384 + c*128 + k] = f2bf(m2w[(size_t)l*16384 + k*128 + c]);
    }
}

// ================= embedding =================
__global__ void embed_kernel(const float* __restrict__ x,
                             const float* __restrict__ emb_w, const float* __restrict__ emb_b,
                             float* __restrict__ h, int N) {
    int idx = blockIdx.x * blockDim.x + threadIdx.x;
    if (idx >= N * HD) return;
    int n = idx >> 7, t = idx & 127;
    float acc = emb_b[t];
    #pragma unroll
    for (int a = 0; a < 21; ++a) acc += x[n*21 + a] * emb_w[a*HD + t];
    h[idx] = acc;
}

// ========= filter table build — bf16 table with cenv folded in ======
__global__ __launch_bounds__(256, 2) void buildtab_kernel(
        const ushort* __restrict__ m1T_all, const ushort* __restrict__ m2T_all,
        const float* __restrict__ m1b_all, const float* __restrict__ m2b_all,
        ushort* __restrict__ Tb6) {
    __shared__ ushort A1[128 * 64];
    __shared__ ushort B1[128 * 64];
    __shared__ ushort U [128 * 128];
    __shared__ float CV[128];
    char* A1b = (char*)A1;
    char* B1b = (char*)B1;
    char* Ub  = (char*)U;
    const int tid  = threadIdx.x;
    const int lane = tid & 63;
    const int wave = tid >> 6;
    const int l15  = lane & 15;
    const int kgrp = (lane >> 4) * 8;
    const int rbase = wave * 32;
    const int NTILES = NTAB2 / 128;
    const int layer = blockIdx.x / NTILES;
    const int mt    = blockIdx.x % NTILES;
    const ushort* m1T = m1T_all + (size_t)layer * 8192;
    const ushort* m2T = m2T_all + (size_t)layer * 16384;
    const float*  m1b = m1b_all + layer * HD;
    const float*  m2b = m2b_all + layer * HD;

    const float step = 10.0f / 49.0f;
    const float coeff = -0.5f / (step * step);
    const float DW = WMAX / (float)(NTAB2 - 1);

    #pragma unroll
    for (int p = 0; p < 4; ++p) {
        int rr = p * 32 + (tid >> 3);
        int k8 = (tid & 7) * 8;
        u16x8 v = *reinterpret_cast<const u16x8*>(&m1T[(size_t)rr * 64 + k8]);
        *reinterpret_cast<u16x8*>(&B1b[rr*128 + ((2*k8) ^ ((rr & 7) << 4))]) = v;
    }
    if (tid < 128) {
        float w = (float)(mt*128 + tid) * DW;
        CV[tid] = 0.5f * (__cosf(w * 0.31415926535897931f) + 1.0f);
    }

    float b1c[8], b2c[8];
    #pragma unroll
    for (int cb = 0; cb < 8; ++cb) { b1c[cb] = m1b[cb*16 + l15]; b2c[cb] = m2b[cb*16 + l15]; }

    #pragma unroll
    for (int p = 0; p < 4; ++p) {
        int rr = p * 32 + (tid >> 3);
        int k8 = (tid & 7) * 8;
        float w = (float)(mt*128 + rr) * DW;
        u16x8 v;
        #pragma unroll
        for (int j = 0; j < 8; ++j) {
            int k = k8 + j;
            float d = w - (float)k * step;
            float g = (k < NGAUSS) ? __expf(coeff * d * d) : 0.0f;
            v[j] = f2bf(g);
        }
        *reinterpret_cast<u16x8*>(&A1b[rr*128 + ((2*k8) ^ ((rr & 7) << 4))]) = v;
    }
    __syncthreads();

    f32x4 acc1[2][8];
    #pragma unroll
    for (int i = 0; i < 2; ++i)
        #pragma unroll
        for (int j = 0; j < 8; ++j) { acc1[i][j].x=0.f; acc1[i][j].y=0.f; acc1[i][j].z=0.f; acc1[i][j].w=0.f; }
    #pragma unroll
    for (int ks = 0; ks < 2; ++ks) {
        int k = ks*32 + kgrp;
        bf16x8 af[2];
        #pragma unroll
        for (int rt = 0; rt < 2; ++rt) {
            int r = rbase + rt*16 + l15;
            af[rt] = *reinterpret_cast<const bf16x8*>(&A1b[r*128 + ((2*k) ^ ((r & 7) << 4))]);
        }
        #pragma unroll
        for (int cb = 0; cb < 8; ++cb) {
            int c = cb*16 + l15;
            bf16x8 bv = *reinterpret_cast<const bf16x8*>(&B1b[c*128 + ((2*k) ^ ((c & 7) << 4))]);
            acc1[0][cb] = __builtin_amdgcn_mfma_f32_16x16x32_bf16(af[0], bv, acc1[0][cb], 0, 0, 0);
            acc1[1][cb] = __builtin_amdgcn_mfma_f32_16x16x32_bf16(af[1], bv, acc1[1][cb], 0, 0, 0);
        }
    }
    #pragma unroll
    for (int rt = 0; rt < 2; ++rt) {
        #pragma unroll
        for (int cb = 0; cb < 8; ++cb) {
            int c = cb*16 + l15;
            #pragma unroll
            for (int i = 0; i < 4; ++i) {
                int rrow = rbase + rt*16 + (lane >> 4)*4 + i;
                ushort us = f2bf(ssp_f(acc1[rt][cb][i] + b1c[cb]));
                *reinterpret_cast<ushort*>(&Ub[rrow*256 + ((2*c) ^ ((rrow & 7) << 4))]) = us;
            }
        }
    }
    __syncthreads();

    f32x4 acc2[2][8];
    #pragma unroll
    for (int i = 0; i < 2; ++i)
        #pragma unroll
        for (int j = 0; j < 8; ++j) { acc2[i][j].x=0.f; acc2[i][j].y=0.f; acc2[i][j].z=0.f; acc2[i][j].w=0.f; }
    #pragma unroll
    for (int kh = 0; kh < 2; ++kh) {
        if (kh) __syncthreads();
        #pragma unroll
        for (int p = 0; p < 4; ++p) {
            int rr = p * 32 + (tid >> 3);
            int kk = (tid & 7) * 8;
            u16x8 v = *reinterpret_cast<const u16x8*>(&m2T[(size_t)rr*128 + kh*64 + kk]);
            *reinterpret_cast<u16x8*>(&A1b[rr*128 + ((2*kk) ^ ((rr & 7) << 4))]) = v;
        }
        __syncthreads();
        #pragma unroll
        for (int ks2 = 0; ks2 < 2; ++ks2) {
            int ku = kh*64 + ks2*32 + kgrp;
            int kb = ks2*32 + kgrp;
            bf16x8 af[2];
            #pragma unroll
            for (int rt = 0; rt < 2; ++rt) {
                int r = rbase + rt*16 + l15;
                af[rt] = *reinterpret_cast<const bf16x8*>(&Ub[r*256 + ((2*ku) ^ ((r & 7) << 4))]);
            }
            #pragma unroll
            for (int cb = 0; cb < 8; ++cb) {
                int c = cb*16 + l15;
                bf16x8 bv = *reinterpret_cast<const bf16x8*>(&A1b[c*128 + ((2*kb) ^ ((c & 7) << 4))]);
                acc2[0][cb] = __builtin_amdgcn_mfma_f32_16x16x32_bf16(af[0], bv, acc2[0][cb], 0, 0, 0);
                acc2[1][cb] = __builtin_amdgcn_mfma_f32_16x16x32_bf16(af[1], bv, acc2[1][cb], 0, 0, 0);
            }
        }
    }
    __syncthreads();   // GEMM2's U reads complete -> U reusable as output stage

    #pragma unroll
    for (int rt = 0; rt < 2; ++rt) {
        #pragma unroll
        for (int cb = 0; cb < 8; ++cb) {
            int c = cb*16 + l15;
            #pragma unroll
            for (int i = 0; i < 4; ++i) {
                int rrow = rbase + rt*16 + (lane >> 4)*4 + i;
                U[rrow*128 + c] = f2bf((acc2[rt][cb][i] + b2c[cb]) * CV[rrow]);
            }
        }
    }
    __syncthreads();
    #pragma unroll
    for (int p = 0; p < 8; ++p) {
        int idx = p * 256 + tid;
        int rr = idx >> 4;
        int k8 = (idx & 15) * 8;
        u16x8 v = *reinterpret_cast<const u16x8*>(&U[rr*128 + k8]);
        *reinterpret_cast<u16x8*>(&Tb6[((size_t)layer*NTAB2 + mt*128 + rr)*HD + k8]) = v;
    }
}

// ============ persistent-weight 64-row GEMV: out = EPI(h @ B) ============
// SPLIT: B = BThi + BTlo (K doubled to 256). !SPLIT: single bf16 B (K=128).
template<int EPI, bool SPLIT>
__global__ __launch_bounds__(256) void gemv64_kernel(
        const float* __restrict__ A, const ushort* __restrict__ BThi,
        const ushort* __restrict__ BTlo, const float* __restrict__ bias,
        float* __restrict__ fdst, ushort* __restrict__ bdst, int mtiles) {
    constexpr int KW   = SPLIT ? 256 : 128;
    constexpr int BROW = 2 * KW;
    __shared__ ushort Bw[128 * KW];
    __shared__ ushort A_[64 * 128];
    char* Bwb = (char*)Bw;
    char* Ab  = (char*)A_;
    const int tid  = threadIdx.x;
    const int lane = tid & 63;
    const int wave = tid >> 6;
    const int l15  = lane & 15;
    const int kgrp = (lane >> 4) * 8;
    const int rbase = wave * 16;

    if (SPLIT) {
        #pragma unroll
        for (int p = 0; p < 16; ++p) {
            int idx = p * 256 + tid;
            int c = idx >> 5;
            int k8 = (idx & 31) * 8;
            const ushort* src = (k8 < 128) ? BThi : BTlo;
            u16x8 v = *reinterpret_cast<const u16x8*>(&src[(size_t)c*128 + (k8 & 127)]);
            *reinterpret_cast<u16x8*>(&Bwb[c*BROW + ((2*k8) ^ ((c & 7) << 4))]) = v;
        }
    } else {
        #pragma unroll
        for (int p = 0; p < 8; ++p) {
            int idx = p * 256 + tid;
            int c = idx >> 4;
            int k8 = (idx & 15) * 8;
            u16x8 v = *reinterpret_cast<const u16x8*>(&BThi[(size_t)c*128 + k8]);
            *reinterpret_cast<u16x8*>(&Bwb[c*BROW + ((2*k8) ^ ((c & 7) << 4))]) = v;
        }
    }
    float bt[8];
    if (EPI == 4) {
        #pragma unroll
        for (int cb = 0; cb < 8; ++cb) bt[cb] = bias[cb*16 + l15];
    }
    __syncthreads();

    for (int mt = blockIdx.x; mt < mtiles; mt += gridDim.x) {
        #pragma unroll
        for (int p = 0; p < 8; ++p) {
            int rr = p * 8 + (tid >> 5);
            int k4 = (tid & 31) * 4;
            f32x4 v = *reinterpret_cast<const f32x4*>(&A[(size_t)(mt*64 + rr)*HD + k4]);
            u16x4 b;
            b.x = f2bf(v.x); b.y = f2bf(v.y); b.z = f2bf(v.z); b.w = f2bf(v.w);
            *reinterpret_cast<u16x4*>(&Ab[rr*256 + ((2*k4) ^ ((rr & 7) << 4))]) = b;
        }
        __syncthreads();

        bf16x8 af[4];
        {
            int r = rbase + l15;
            #pragma unroll
            for (int q = 0; q < 4; ++q)
                af[q] = *reinterpret_cast<const bf16x8*>(&Ab[r*256 + ((2*(q*32 + kgrp)) ^ ((r & 7) << 4))]);
        }
        f32x4 acc[8];
        #pragma unroll
        for (int j = 0; j < 8; ++j) { acc[j].x=0.f; acc[j].y=0.f; acc[j].z=0.f; acc[j].w=0.f; }
        #pragma unroll
        for (int ks = 0; ks < (SPLIT ? 8 : 4); ++ks) {
            int kB = ks*32 + kgrp;
            #pragma unroll
            for (int cb = 0; cb < 8; ++cb) {
                int c = cb*16 + l15;
                bf16x8 bv = *reinterpret_cast<const bf16x8*>(&Bwb[c*BROW + ((2*kB) ^ ((c & 7) << 4))]);
                acc[cb] = __builtin_amdgcn_mfma_f32_16x16x32_bf16(af[ks & 3], bv, acc[cb], 0, 0, 0);
            }
        }

        #pragma unroll
        for (int cb = 0; cb < 8; ++cb) {
            int c = cb*16 + l15;
            #pragma unroll
            for (int i = 0; i < 4; ++i) {
                int row = mt*64 + rbase + (lane >> 4)*4 + i;
                size_t off = (size_t)row * HD + c;
                if (EPI == 4) fdst[off] = fmaxf(acc[cb][i] + bt[cb], 0.0f);
                else          bdst[off] = f2bf(acc[cb][i]);
            }
        }
        __syncthreads();
    }
}

// ======== persistent-weight fused node block (32-row tiles, 512 threads) ========
// GEMM1: t = ssp(aggb @ c2 + c2b)          [c2 single bf16, W1 32KB]
// GEMM2: hv = h + t @ (lwhi+lwlo) + lb -> h [lw split, W2 64KB]
// CHAIN: GEMM3: hxbn = bf16(hv @ c1n)       [c1n single bf16, W3 32KB]
// LDS: 32+64+32+8 = 136 KB -> 1 block/CU.
template<bool CHAIN>
__global__ __launch_bounds__(512, 1) void nodefused_kernel(
        const ushort* __restrict__ aggb,
        const ushort* __restrict__ c2T, const float* __restrict__ c2b,
        const ushort* __restrict__ lwhi, const ushort* __restrict__ lwlo,
        const float* __restrict__ lb,
        const ushort* __restrict__ c1nT,
        float* __restrict__ h, ushort* __restrict__ hxbn, int mtiles) {
    __shared__ ushort W1[128 * 128];   // 32KB c2 single
    __shared__ ushort W2[128 * 256];   // 64KB lw split
    __shared__ ushort W3[128 * 128];   // 32KB c1-next single
    __shared__ ushort BUF[32 * 128];   // 8KB (A, U, then hv)
    char* W1b = (char*)W1;
    char* W2b = (char*)W2;
    char* W3b = (char*)W3;
    char* Bu  = (char*)BUF;
    const int tid  = threadIdx.x;
    const int lane = tid & 63;
    const int wave = tid >> 6;
    const int l15  = lane & 15;
    const int kgrp = (lane >> 4) * 8;
    const int wr = (wave & 1) * 16;
    const int wc = (wave >> 1) * 2;

    // stage weights once
    #pragma unroll
    for (int p = 0; p < 4; ++p) {
        int idx = p * 512 + tid;           // 0..2047
        int c = idx >> 4;
        int k8 = (idx & 15) * 8;
        u16x8 v1 = *reinterpret_cast<const u16x8*>(&c2T[(size_t)c*128 + k8]);
        *reinterpret_cast<u16x8*>(&W1b[c*256 + ((2*k8) ^ ((c & 7) << 4))]) = v1;
        if (CHAIN) {
            u16x8 v3 = *reinterpret_cast<const u16x8*>(&c1nT[(size_t)c*128 + k8]);
            *reinterpret_cast<u16x8*>(&W3b[c*256 + ((2*k8) ^ ((c & 7) << 4))]) = v3;
        }
    }
    #pragma unroll
    for (int p = 0; p < 8; ++p) {
        int idx = p * 512 + tid;
        int c = idx >> 5;
        int k8 = (idx & 31) * 8;
        const ushort* s2 = (k8 < 128) ? lwhi : lwlo;
        u16x8 v2 = *reinterpret_cast<const u16x8*>(&s2[(size_t)c*128 + (k8 & 127)]);
        *reinterpret_cast<u16x8*>(&W2b[c*512 + ((2*k8) ^ ((c & 7) << 4))]) = v2;
    }
    float b1c[2], b2c[2];
    #pragma unroll
    for (int cb = 0; cb < 2; ++cb) {
        int c = (wc + cb)*16 + l15;
        b1c[cb] = c2b[c];
        b2c[cb] = lb[c];
    }
    __syncthreads();

    for (int mt = blockIdx.x; mt < mtiles; mt += gridDim.x) {
        // stage A = aggb tile; prefetch h
        {
            int rr = tid >> 4;
            int k8 = (tid & 15) * 8;
            u16x8 v = *reinterpret_cast<const u16x8*>(&aggb[(size_t)(mt*32 + rr)*HD + k8]);
            *reinterpret_cast<u16x8*>(&Bu[rr*256 + ((2*k8) ^ ((rr & 7) << 4))]) = v;
        }
        float hp[2][4];
        #pragma unroll
        for (int cb = 0; cb < 2; ++cb) {
            int c = (wc + cb)*16 + l15;
            #pragma unroll
            for (int i = 0; i < 4; ++i) {
                int row = mt*32 + wr + (lane >> 4)*4 + i;
                hp[cb][i] = h[(size_t)row * HD + c];
            }
        }
        __syncthreads();   // (1) A visible

        // ---- GEMM1: acc = A @ c2 (K=128 single) ----
        bf16x8 af[4];
        {
            int r = wr + l15;
            #pragma unroll
            for (int q = 0; q < 4; ++q)
                af[q] = *reinterpret_cast<const bf16x8*>(&Bu[r*256 + ((2*(q*32 + kgrp)) ^ ((r & 7) << 4))]);
        }
        f32x4 acc[2];
        #pragma unroll
        for (int j = 0; j < 2; ++j) { acc[j].x=0.f; acc[j].y=0.f; acc[j].z=0.f; acc[j].w=0.f; }
        #pragma unroll
        for (int ks = 0; ks < 4; ++ks) {
            int kB = ks*32 + kgrp;
            #pragma unroll
            for (int cb = 0; cb < 2; ++cb) {
                int c = (wc + cb)*16 + l15;
                bf16x8 bv = *reinterpret_cast<const bf16x8*>(&W1b[c*256 + ((2*kB) ^ ((c & 7) << 4))]);
                acc[cb] = __builtin_amdgcn_mfma_f32_16x16x32_bf16(af[ks], bv, acc[cb], 0, 0, 0);
            }
        }
        __syncthreads();   // (2) A reads done -> BUF reusable

        // epilogue1: ssp -> BUF (U role)
        #pragma unroll
        for (int cb = 0; cb < 2; ++cb) {
            int c = (wc + cb)*16 + l15;
            #pragma unroll
            for (int i = 0; i < 4; ++i) {
                int rrow = wr + (lane >> 4)*4 + i;
                ushort us = f2bf(ssp_f(acc[cb][i] + b1c[cb]));
                *reinterpret_cast<ushort*>(&Bu[rrow*256 + ((2*c) ^ ((rrow & 7) << 4))]) = us;
            }
        }
        __syncthreads();   // (3) U visible

        // ---- GEMM2: acc = U @ lw' (K=256 split) ----
        {
            int r = wr + l15;
            #pragma unroll
            for (int q = 0; q < 4; ++q)
                af[q] = *reinterpret_cast<const bf16x8*>(&Bu[r*256 + ((2*(q*32 + kgrp)) ^ ((r & 7) << 4))]);
        }
        #pragma unroll
        for (int j = 0; j < 2; ++j) { acc[j].x=0.f; acc[j].y=0.f; acc[j].z=0.f; acc[j].w=0.f; }
        #pragma unroll
        for (int ks = 0; ks < 8; ++ks) {
            int kB = ks*32 + kgrp;
            #pragma unroll
            for (int cb = 0; cb < 2; ++cb) {
                int c = (wc + cb)*16 + l15;
                bf16x8 bv = *reinterpret_cast<const bf16x8*>(&W2b[c*512 + ((2*kB) ^ ((c & 7) << 4))]);
                acc[cb] = __builtin_amdgcn_mfma_f32_16x16x32_bf16(af[ks & 3], bv, acc[cb], 0, 0, 0);
            }
        }
        // epilogue2: hv = h + acc + lb -> h (keep hv in regs)
        float hv[2][4];
        #pragma unroll
        for (int cb = 0; cb < 2; ++cb) {
            int c = (wc + cb)*16 + l15;
            #pragma unroll
            for (int i = 0; i < 4; ++i) {
                int row = mt*32 + wr + (lane >> 4)*4 + i;
                hv[cb][i] = hp[cb][i] + acc[cb][i] + b2c[cb];
                h[(size_t)row * HD + c] = hv[cb][i];
            }
        }
        __syncthreads();   // (4) GEMM2's U reads done -> BUF reusable

        if (CHAIN) {
            // stage bf16(hv) -> BUF
            #pragma unroll
            for (int cb = 0; cb < 2; ++cb) {
                int c = (wc + cb)*16 + l15;
                #pragma unroll
                for (int i = 0; i < 4; ++i) {
                    int rrow = wr + (lane >> 4)*4 + i;
                    *reinterpret_cast<ushort*>(&Bu[rrow*256 + ((2*c) ^ ((rrow & 7) << 4))]) = f2bf(hv[cb][i]);
                }
            }
            __syncthreads();   // (5) hv tile visible

            // ---- GEMM3: acc = hv @ c1n (K=128 single) ----
            {
                int r = wr + l15;
                #pragma unroll
                for (int q = 0; q < 4; ++q)
                    af[q] = *reinterpret_cast<const bf16x8*>(&Bu[r*256 + ((2*(q*32 + kgrp)) ^ ((r & 7) << 4))]);
            }
            #pragma unroll
            for (int j = 0; j < 2; ++j) { acc[j].x=0.f; acc[j].y=0.f; acc[j].z=0.f; acc[j].w=0.f; }
            #pragma unroll
            for (int ks = 0; ks < 4; ++ks) {
                int kB = ks*32 + kgrp;
                #pragma unroll
                for (int cb = 0; cb < 2; ++cb) {
                    int c = (wc + cb)*16 + l15;
                    bf16x8 bv = *reinterpret_cast<const bf16x8*>(&W3b[c*256 + ((2*kB) ^ ((c & 7) << 4))]);
                    acc[cb] = __builtin_amdgcn_mfma_f32_16x16x32_bf16(af[ks], bv, acc[cb], 0, 0, 0);
                }
            }
            // epilogue3: hxbn = bf16(acc)   (c1 has no bias)
            #pragma unroll
            for (int cb = 0; cb < 2; ++cb) {
                int c = (wc + cb)*16 + l15;
                #pragma unroll
                for (int i = 0; i < 4; ++i) {
                    int row = mt*32 + wr + (lane >> 4)*4 + i;
                    hxbn[(size_t)row * HD + c] = f2bf(acc[cb][i]);
                }
            }
            __syncthreads();   // (6) BUF reads done before next tile
        }
    }
}

// ========= fused gather-NN-segment-sum (16-slot, software-pipelined meta) =========
__global__ __launch_bounds__(256) void gathersum_kernel(
        const ushort* __restrict__ Tb, const uint* __restrict__ meta,
        const int* __restrict__ rowp, const ushort* __restrict__ hxb,
        ushort* __restrict__ aggb, int N) {
    const int lane = threadIdx.x & 63;
    const int n = blockIdx.x * 4 + (threadIdx.x >> 6);
    if (n >= N) return;
    const int c0 = lane * 2;
    const int s0 = rowp[n], s1 = rowp[n + 1];
    float al[4] = {0.f, 0.f, 0.f, 0.f};
    float ah[4] = {0.f, 0.f, 0.f, 0.f};
    int s = s0;
    uint m[16];
    if (s + 16 <= s1) {
        #pragma unroll
        for (int k = 0; k < 16; ++k) m[k] = meta[s + k];
    }
    while (s + 16 <= s1) {
        // issue gathers for current block
        uint tv[16], hv[16];
        #pragma unroll
        for (int k = 0; k < 16; ++k) {
            tv[k] = *reinterpret_cast<const uint*>(&Tb[(size_t)(m[k] >> 16) * HD + c0]);
            hv[k] = *reinterpret_cast<const uint*>(&hxb[(size_t)(m[k] & 0xFFFFu) * HD + c0]);
        }
        // prefetch next block's meta (hides under gather latency + FMAs)
        const int sn = s + 16;
        uint mn[16];
        const bool haveN = (sn + 16 <= s1);
        if (haveN) {
            #pragma unroll
            for (int k = 0; k < 16; ++k) mn[k] = meta[sn + k];
        }
        // FMAs for current block (same accumulation order as before)
        #pragma unroll
        for (int k = 0; k < 16; ++k) {
            al[k & 3] += __uint_as_float(tv[k] << 16) * __uint_as_float(hv[k] << 16);
            ah[k & 3] += __uint_as_float(tv[k] & 0xFFFF0000u) * __uint_as_float(hv[k] & 0xFFFF0000u);
        }
        s = sn;
        if (haveN) {
            #pragma unroll
            for (int k = 0; k < 16; ++k) m[k] = mn[k];
        }
    }
    for (; s + 4 <= s1; s += 4) {
        uint m4[4], tv[4], hv[4];
        #pragma unroll
        for (int k = 0; k < 4; ++k) m4[k] = meta[s + k];
        #pragma unroll
        for (int k = 0; k < 4; ++k) {
            tv[k] = *reinterpret_cast<const uint*>(&Tb[(size_t)(m4[k] >> 16) * HD + c0]);
            hv[k] = *reinterpret_cast<const uint*>(&hxb[(size_t)(m4[k] & 0xFFFFu) * HD + c0]);
        }
        #pragma unroll
        for (int k = 0; k < 4; ++k) {
            al[k] += __uint_as_float(tv[k] << 16) * __uint_as_float(hv[k] << 16);
            ah[k] += __uint_as_float(tv[k] & 0xFFFF0000u) * __uint_as_float(hv[k] & 0xFFFF0000u);
        }
    }
    for (; s < s1; ++s) {
        uint m0 = meta[s];
        uint tv = *reinterpret_cast<const uint*>(&Tb[(size_t)(m0 >> 16) * HD + c0]);
        uint hv = *reinterpret_cast<const uint*>(&hxb[(size_t)(m0 & 0xFFFFu) * HD + c0]);
        al[0] += __uint_as_float(tv << 16) * __uint_as_float(hv << 16);
        ah[0] += __uint_as_float(tv & 0xFFFF0000u) * __uint_as_float(hv & 0xFFFF0000u);
    }
    float lo = (al[0] + al[1]) + (al[2] + al[3]);
    float hi = (ah[0] + ah[1]) + (ah[2] + ah[3]);
    uint out = ((uint)f2bf(lo)) | (((uint)f2bf(hi)) << 16);
    *reinterpret_cast<uint*>(&aggb[(size_t)n * HD + c0]) = out;
}

// ================= mean pool =================
__global__ void pool_kernel(const float* __restrict__ h1, const int* __restrict__ batch,
                            float* __restrict__ gsum, float* __restrict__ gcnt, int N) {
    __shared__ float pool[NGRAPH][HD];
    __shared__ float cnt[NGRAPH];
    const int t = threadIdx.x;
    #pragma unroll
    for (int g = 0; g < NGRAPH; ++g) pool[g][t] = 0.0f;
    if (t < NGRAPH) cnt[t] = 0.0f;
    __syncthreads();
    int chunk = (N + gridDim.x - 1) / gridDim.x;
    int n0 = blockIdx.x * chunk, n1 = min(N, n0 + chunk);
    for (int n = n0; n < n1; ++n) {
        int b = batch[n];
        pool[b][t] += h1[(size_t)n * HD + t];
        if (t == 0) cnt[b] += 1.0f;
    }
    __syncthreads();
    #pragma unroll
    for (int g = 0; g < NGRAPH; ++g) atomicAdd(&gsum[g*HD + t], pool[g][t]);
    if (t < NGRAPH) atomicAdd(&gcnt[t], cnt[t]);
}

// ================= head =================
__global__ void finalize_kernel(const float* __restrict__ gsum, const float* __restrict__ gcnt,
                                const float* __restrict__ l1w, const float* __restrict__ l1b,
                                const float* __restrict__ l2w, const float* __restrict__ l2b,
                                float* __restrict__ d_out) {
    __shared__ float ge[HD];
    __shared__ float h2[HD];
    const int g = blockIdx.x, t = threadIdx.x;
    float cnt = fmaxf(gcnt[g], 1.0f);
    float v = gsum[g*HD + t] / cnt;
    d_out[g*HD + t] = v;
    ge[t] = v;
    __syncthreads();
    float acc = l1b[t];
    #pragma unroll 8
    for (int k = 0; k < HD; ++k) acc += ge[k] * l1w[k*HD + t];
    h2[t] = fmaxf(acc, 0.0f);
    __syncthreads();
    if (t < NCLS) {
        float o = l2b[t];
        #pragma unroll 8
        for (int k = 0; k < HD; ++k) o += h2[k] * l2w[k*NCLS + t];
        d_out[NGRAPH*HD + g*NCLS + t] = o;
    }
}

extern "C" void kernel_launch(void* const* d_in, const int* in_sizes, int n_in,
                              void* d_out, int out_size, void* d_ws, size_t ws_size,
                              hipStream_t stream) {
    const float* x     = (const float*)d_in[0];
    const float* pos   = (const float*)d_in[1];
    const int*   eidx  = (const int*)d_in[2];
    const int*   batch = (const int*)d_in[3];
    const float* emb_w = (const float*)d_in[4];
    const float* emb_b = (const float*)d_in[5];
    const float* m1w   = (const float*)d_in[6];
    const float* m1b   = (const float*)d_in[7];
    const float* m2w   = (const float*)d_in[8];
    const float* m2b   = (const float*)d_in[9];
    const float* c1w   = (const float*)d_in[10];
    const float* c2w   = (const float*)d_in[11];
    const float* c2b   = (const float*)d_in[12];
    const float* lw    = (const float*)d_in[13];
    const float* lb    = (const float*)d_in[14];
    const float* l1w   = (const float*)d_in[15];
    const float* l1b   = (const float*)d_in[16];
    const float* l2w   = (const float*)d_in[17];
    const float* l2b   = (const float*)d_in[18];

    const int N = in_sizes[0] / 21;          // 20000
    const int E = in_sizes[2] / 2;           // 640000
    const int* row = eidx;
    const int* col = eidx + E;
    const int NT64 = (N + 63) / 64;          // 313
    const int NT32 = (N + 31) / 32;          // 625
    const int NB   = (N + 255) / 256;        // 79
    const int Npad = NT64 * 64 + 64;

    size_t off = 0;
    char* base = (char*)d_ws;
    auto alloc = [&](size_t bytes) -> void* {
        off = (off + 255) & ~(size_t)255;
        void* p = base + off;
        off += bytes;
        return p;
    };
    int*    deg     = (int*)alloc((size_t)N * 4);
    int*    cursor  = (int*)alloc((size_t)N * 4);
    int*    rowp    = (int*)alloc((size_t)(N + 1) * 4);
    int*    bsum    = (int*)alloc(512 * 4);
    int*    boff    = (int*)alloc(512 * 4);
    uint*   meta    = (uint*)alloc((size_t)E * 4);
    float*  h       = (float*)alloc((size_t)Npad * HD * 4);
    ushort* hxb     = (ushort*)alloc((size_t)Npad * HD * 2);
    ushort* aggb    = (ushort*)alloc((size_t)Npad * HD * 2);
    float*  h1      = (float*)alloc((size_t)Npad * HD * 4);
    ushort* Tb6     = (ushort*)alloc((size_t)6 * NTAB2 * HD * 2);
    ushort* m1T     = (ushort*)alloc((size_t)6 * 128 * 64 * 2);
    ushort* nodeThi = (ushort*)alloc((size_t)19 * 128 * 128 * 2);
    ushort* nodeTlo = (ushort*)alloc((size_t)19 * 128 * 128 * 2);
    ushort* m2T     = (ushort*)alloc((size_t)6 * 128 * 128 * 2);
    float*  gsum    = (float*)alloc((size_t)NGRAPH * HD * 4);
    float*  gcnt    = (float*)alloc((size_t)NGRAPH * 4);

    // ---- one-time: weight prep + CSR + filter tables ----
    prep_kernel<<<1792, 256, 0, stream>>>(m1w, c1w, c2w, lw, l1w, m2w,
                                          m1T, nodeThi, nodeTlo, m2T);
    hipMemsetAsync(deg, 0, (size_t)N * 4, stream);
    hist_kernel<<<(E + 255)/256, 256, 0, stream>>>(col, deg, E);
    scan1_kernel<<<NB, 256, 0, stream>>>(deg, rowp, bsum, N);
    scan2_kernel<<<1, 256, 0, stream>>>(bsum, boff, NB, rowp + N);
    scan3_kernel<<<NB, 256, 0, stream>>>(rowp, boff, cursor, N);
    fill_kernel<<<(E + 255)/256, 256, 0, stream>>>(row, col, pos, cursor, meta, E);
    buildtab_kernel<<<6 * (NTAB2/128), 256, 0, stream>>>(m1T, m2T, m1b, m2b, Tb6);
    embed_kernel<<<(N*HD + 255)/256, 256, 0, stream>>>(x, emb_w, emb_b, h, N);

    // hxb for layer 0 (single-bf16 c1)
    gemv64_kernel<5, false><<<NT64, 256, 0, stream>>>(h, nodeThi, nullptr, nullptr,
                                                      nullptr, hxb, NT64);

    for (int l = 0; l < NLAYER; ++l) {
        const ushort* c2T  = nodeThi + (size_t)(6 + l) * 16384;   // single bf16
        const ushort* lThi = nodeThi + (size_t)(12 + l) * 16384;
        const ushort* lTlo = nodeTlo + (size_t)(12 + l) * 16384;

        gathersum_kernel<<<(N + 3)/4, 256, 0, stream>>>(
            Tb6 + (size_t)l * NTAB2 * HD, meta, rowp, hxb, aggb, N);

        if (l < NLAYER - 1) {
            const ushort* c1nT = nodeThi + (size_t)(l + 1) * 16384;
            nodefused_kernel<true><<<256, 512, 0, stream>>>(
                aggb, c2T, c2b + l*HD, lThi, lTlo, lb + l*HD, c1nT, h, hxb, NT32);
        } else {
            nodefused_kernel<false><<<256, 512, 0, stream>>>(
                aggb, c2T, c2b + l*HD, lThi, lTlo, lb + l*HD, nullptr, h, nullptr, NT32);
            // head: h1 = relu(h @ lin1 + b1)  (split, bit-identical path)
            gemv64_kernel<4, true><<<NT64, 256, 0, stream>>>(
                h, nodeThi + (size_t)18 * 16384, nodeTlo + (size_t)18 * 16384,
                l1b, h1, nullptr, NT64);
        }
    }

    hipMemsetAsync(gsum, 0, (size_t)(NGRAPH*HD + NGRAPH) * 4, stream);
    pool_kernel<<<256, HD, 0, stream>>>(h1, batch, gsum, gcnt, N);
    finalize_kernel<<<NGRAPH, HD, 0, stream>>>(gsum, gcnt, l1w, l1b, l2w, l2b,
                                               (float*)d_out);
}

// Round 19
// 409.837 us; speedup vs baseline: 1.0094x; 1.0094x over previous
//
#include <hip/hip_runtime.h>
#include <hip/hip_bf16.h>

#define HD 128
#define NGAUSS 50
#define NLAYER 6
#define NGRAPH 16
#define NCLS 97
#define NTAB2 4096
#define WMAX 12.0f

typedef __attribute__((ext_vector_type(8))) short bf16x8;
typedef __attribute__((ext_vector_type(4))) float f32x4;
typedef __attribute__((ext_vector_type(8))) ushort u16x8;
typedef __attribute__((ext_vector_type(4))) ushort u16x4;

__device__ __forceinline__ float ssp_f(float x) {
    float e = __expf(-fabsf(x));
    return fmaxf(x, 0.0f) + __logf(0.5f + 0.5f * e);
}
__device__ __forceinline__ ushort f2bf(float f) {   // RNE f32->bf16
    uint u = __float_as_uint(f);
    return (ushort)((u + 0x7FFFu + ((u >> 16) & 1u)) >> 16);
}
__device__ __forceinline__ float bf2f(ushort s) {
    return __uint_as_float(((uint)s) << 16);
}

// ================= CSR build =================
__global__ void hist_kernel(const int* __restrict__ col, int* __restrict__ deg, int E) {
    int e = blockIdx.x * blockDim.x + threadIdx.x;
    if (e < E) atomicAdd(&deg[col[e]], 1);
}

__global__ void scan1_kernel(const int* __restrict__ deg, int* __restrict__ rowp,
                             int* __restrict__ bsum, int N) {
    __shared__ int sm[256];
    const int t = threadIdx.x, i = blockIdx.x * 256 + t;
    int v = (i < N) ? deg[i] : 0;
    sm[t] = v;
    __syncthreads();
    for (int off = 1; off < 256; off <<= 1) {
        int x = sm[t];
        int a = (t >= off) ? sm[t - off] : 0;
        __syncthreads();
        sm[t] = x + a;
        __syncthreads();
    }
    if (i < N) rowp[i] = sm[t] - v;
    if (t == 255) bsum[blockIdx.x] = sm[255];
}
__global__ void scan2_kernel(const int* __restrict__ bsum, int* __restrict__ boff,
                             int NB, int* __restrict__ rowpN) {
    __shared__ int sm[256];
    const int t = threadIdx.x;
    int v = (t < NB) ? bsum[t] : 0;
    sm[t] = v;
    __syncthreads();
    for (int off = 1; off < 256; off <<= 1) {
        int x = sm[t];
        int a = (t >= off) ? sm[t - off] : 0;
        __syncthreads();
        sm[t] = x + a;
        __syncthreads();
    }
    if (t < NB) boff[t] = sm[t] - v;
    if (t == 255) *rowpN = sm[255];
}
__global__ void scan3_kernel(int* __restrict__ rowp, const int* __restrict__ boff,
                             int* __restrict__ cursor, int N) {
    int i = blockIdx.x * blockDim.x + threadIdx.x;
    if (i < N) {
        int r = rowp[i] + boff[i >> 8];
        rowp[i] = r;
        cursor[i] = r;
    }
}

// per-slot metadata (4 B): row | (nearest_tab_idx << 16). cenv folded into table.
__global__ void fill_kernel(const int* __restrict__ row, const int* __restrict__ col,
                            const float* __restrict__ pos, int* __restrict__ cursor,
                            uint* __restrict__ meta, int E) {
    int e = blockIdx.x * blockDim.x + threadIdx.x;
    if (e >= E) return;
    int c = col[e], r = row[e];
    int slot = atomicAdd(&cursor[c], 1);
    float dx = pos[r*3+0] - pos[c*3+0];
    float dy = pos[r*3+1] - pos[c*3+1];
    float dz = pos[r*3+2] - pos[c*3+2];
    float w = sqrtf(dx*dx + dy*dy + dz*dz);
    const float invDW = (float)(NTAB2 - 1) / WMAX;
    int i = (int)(w * invDW + 0.5f);     // nearest neighbor
    i = min(i, NTAB2 - 1);
    meta[slot] = ((uint)r) | (((uint)i) << 16);
}

// ================= weight prep =================
__global__ void prep_kernel(const float* __restrict__ m1w, const float* __restrict__ c1w,
                            const float* __restrict__ c2w, const float* __restrict__ lw,
                            const float* __restrict__ l1w, const float* __restrict__ m2w,
                            ushort* __restrict__ m1T, ushort* __restrict__ nodeThi,
                            ushort* __restrict__ nodeTlo, ushort* __restrict__ m2T) {
    int idx = blockIdx.x * blockDim.x + threadIdx.x;
    const int S1 = 6*128*64, S2 = 19*128*128, S3 = 6*128*128;
    if (idx < S1) {
        int l = idx / 8192, r = idx % 8192, c = r / 64, k = r % 64;
        float v = (k < NGAUSS) ? m1w[(size_t)l*NGAUSS*128 + k*128 + c] : 0.0f;
        m1T[(size_t)l*8192 + c*64 + k] = f2bf(v);
    } else if (idx < S1 + S2) {
        int j = idx - S1;
        int m = j / 16384, r = j % 16384, c = r / 128, k = r % 128;
        const float* src;
        if (m < 6)       src = c1w + (size_t)m*16384;
        else if (m < 12) src = c2w + (size_t)(m-6)*16384;
        else if (m < 18) src = lw  + (size_t)(m-12)*16384;
        else             src = l1w;
        float v = src[k*128 + c];
        ushort hi = f2bf(v);
        nodeThi[(size_t)m*16384 + c*128 + k] = hi;
        nodeTlo[(size_t)m*16384 + c*128 + k] = f2bf(v - bf2f(hi));
    } else if (idx < S1 + S2 + S3) {
        int j = idx - S1 - S2;
        int l = j / 16384, r = j % 16384, c = r / 128, k = r % 128;
        m2T[(size_t)l*16384 + c*128 + k] = f2bf(m2w[(size_t)l*16384 + k*128 + c]);
    }
}

// ================= embedding =================
__global__ void embed_kernel(const float* __restrict__ x,
                             const float* __restrict__ emb_w, const float* __restrict__ emb_b,
                             float* __restrict__ h, int N) {
    int idx = blockIdx.x * blockDim.x + threadIdx.x;
    if (idx >= N * HD) return;
    int n = idx >> 7, t = idx & 127;
    float acc = emb_b[t];
    #pragma unroll
    for (int a = 0; a < 21; ++a) acc += x[n*21 + a] * emb_w[a*HD + t];
    h[idx] = acc;
}

// ========= filter table build — bf16 table with cenv folded in ======
__global__ __launch_bounds__(256, 2) void buildtab_kernel(
        const ushort* __restrict__ m1T_all, const ushort* __restrict__ m2T_all,
        const float* __restrict__ m1b_all, const float* __restrict__ m2b_all,
        ushort* __restrict__ Tb6) {
    __shared__ ushort A1[128 * 64];
    __shared__ ushort B1[128 * 64];
    __shared__ ushort U [128 * 128];
    __shared__ float CV[128];
    char* A1b = (char*)A1;
    char* B1b = (char*)B1;
    char* Ub  = (char*)U;
    const int tid  = threadIdx.x;
    const int lane = tid & 63;
    const int wave = tid >> 6;
    const int l15  = lane & 15;
    const int kgrp = (lane >> 4) * 8;
    const int rbase = wave * 32;
    const int NTILES = NTAB2 / 128;
    const int layer = blockIdx.x / NTILES;
    const int mt    = blockIdx.x % NTILES;
    const ushort* m1T = m1T_all + (size_t)layer * 8192;
    const ushort* m2T = m2T_all + (size_t)layer * 16384;
    const float*  m1b = m1b_all + layer * HD;
    const float*  m2b = m2b_all + layer * HD;

    const float step = 10.0f / 49.0f;
    const float coeff = -0.5f / (step * step);
    const float DW = WMAX / (float)(NTAB2 - 1);

    #pragma unroll
    for (int p = 0; p < 4; ++p) {
        int rr = p * 32 + (tid >> 3);
        int k8 = (tid & 7) * 8;
        u16x8 v = *reinterpret_cast<const u16x8*>(&m1T[(size_t)rr * 64 + k8]);
        *reinterpret_cast<u16x8*>(&B1b[rr*128 + ((2*k8) ^ ((rr & 7) << 4))]) = v;
    }
    if (tid < 128) {
        float w = (float)(mt*128 + tid) * DW;
        CV[tid] = 0.5f * (__cosf(w * 0.31415926535897931f) + 1.0f);
    }

    float b1c[8], b2c[8];
    #pragma unroll
    for (int cb = 0; cb < 8; ++cb) { b1c[cb] = m1b[cb*16 + l15]; b2c[cb] = m2b[cb*16 + l15]; }

    #pragma unroll
    for (int p = 0; p < 4; ++p) {
        int rr = p * 32 + (tid >> 3);
        int k8 = (tid & 7) * 8;
        float w = (float)(mt*128 + rr) * DW;
        u16x8 v;
        #pragma unroll
        for (int j = 0; j < 8; ++j) {
            int k = k8 + j;
            float d = w - (float)k * step;
            float g = (k < NGAUSS) ? __expf(coeff * d * d) : 0.0f;
            v[j] = f2bf(g);
        }
        *reinterpret_cast<u16x8*>(&A1b[rr*128 + ((2*k8) ^ ((rr & 7) << 4))]) = v;
    }
    __syncthreads();

    f32x4 acc1[2][8];
    #pragma unroll
    for (int i = 0; i < 2; ++i)
        #pragma unroll
        for (int j = 0; j < 8; ++j) { acc1[i][j].x=0.f; acc1[i][j].y=0.f; acc1[i][j].z=0.f; acc1[i][j].w=0.f; }
    #pragma unroll
    for (int ks = 0; ks < 2; ++ks) {
        int k = ks*32 + kgrp;
        bf16x8 af[2];
        #pragma unroll
        for (int rt = 0; rt < 2; ++rt) {
            int r = rbase + rt*16 + l15;
            af[rt] = *reinterpret_cast<const bf16x8*>(&A1b[r*128 + ((2*k) ^ ((r & 7) << 4))]);
        }
        #pragma unroll
        for (int cb = 0; cb < 8; ++cb) {
            int c = cb*16 + l15;
            bf16x8 bv = *reinterpret_cast<const bf16x8*>(&B1b[c*128 + ((2*k) ^ ((c & 7) << 4))]);
            acc1[0][cb] = __builtin_amdgcn_mfma_f32_16x16x32_bf16(af[0], bv, acc1[0][cb], 0, 0, 0);
            acc1[1][cb] = __builtin_amdgcn_mfma_f32_16x16x32_bf16(af[1], bv, acc1[1][cb], 0, 0, 0);
        }
    }
    #pragma unroll
    for (int rt = 0; rt < 2; ++rt) {
        #pragma unroll
        for (int cb = 0; cb < 8; ++cb) {
            int c = cb*16 + l15;
            #pragma unroll
            for (int i = 0; i < 4; ++i) {
                int rrow = rbase + rt*16 + (lane >> 4)*4 + i;
                ushort us = f2bf(ssp_f(acc1[rt][cb][i] + b1c[cb]));
                *reinterpret_cast<ushort*>(&Ub[rrow*256 + ((2*c) ^ ((rrow & 7) << 4))]) = us;
            }
        }
    }
    __syncthreads();

    f32x4 acc2[2][8];
    #pragma unroll
    for (int i = 0; i < 2; ++i)
        #pragma unroll
        for (int j = 0; j < 8; ++j) { acc2[i][j].x=0.f; acc2[i][j].y=0.f; acc2[i][j].z=0.f; acc2[i][j].w=0.f; }
    #pragma unroll
    for (int kh = 0; kh < 2; ++kh) {
        if (kh) __syncthreads();
        #pragma unroll
        for (int p = 0; p < 4; ++p) {
            int rr = p * 32 + (tid >> 3);
            int kk = (tid & 7) * 8;
            u16x8 v = *reinterpret_cast<const u16x8*>(&m2T[(size_t)rr*128 + kh*64 + kk]);
            *reinterpret_cast<u16x8*>(&A1b[rr*128 + ((2*kk) ^ ((rr & 7) << 4))]) = v;
        }
        __syncthreads();
        #pragma unroll
        for (int ks2 = 0; ks2 < 2; ++ks2) {
            int ku = kh*64 + ks2*32 + kgrp;
            int kb = ks2*32 + kgrp;
            bf16x8 af[2];
            #pragma unroll
            for (int rt = 0; rt < 2; ++rt) {
                int r = rbase + rt*16 + l15;
                af[rt] = *reinterpret_cast<const bf16x8*>(&Ub[r*256 + ((2*ku) ^ ((r & 7) << 4))]);
            }
            #pragma unroll
            for (int cb = 0; cb < 8; ++cb) {
                int c = cb*16 + l15;
                bf16x8 bv = *reinterpret_cast<const bf16x8*>(&A1b[c*128 + ((2*kb) ^ ((c & 7) << 4))]);
                acc2[0][cb] = __builtin_amdgcn_mfma_f32_16x16x32_bf16(af[0], bv, acc2[0][cb], 0, 0, 0);
                acc2[1][cb] = __builtin_amdgcn_mfma_f32_16x16x32_bf16(af[1], bv, acc2[1][cb], 0, 0, 0);
            }
        }
    }
    __syncthreads();   // GEMM2's U reads complete -> U reusable as output stage

    #pragma unroll
    for (int rt = 0; rt < 2; ++rt) {
        #pragma unroll
        for (int cb = 0; cb < 8; ++cb) {
            int c = cb*16 + l15;
            #pragma unroll
            for (int i = 0; i < 4; ++i) {
                int rrow = rbase + rt*16 + (lane >> 4)*4 + i;
                U[rrow*128 + c] = f2bf((acc2[rt][cb][i] + b2c[cb]) * CV[rrow]);
            }
        }
    }
    __syncthreads();
    #pragma unroll
    for (int p = 0; p < 8; ++p) {
        int idx = p * 256 + tid;
        int rr = idx >> 4;
        int k8 = (idx & 15) * 8;
        u16x8 v = *reinterpret_cast<const u16x8*>(&U[rr*128 + k8]);
        *reinterpret_cast<u16x8*>(&Tb6[((size_t)layer*NTAB2 + mt*128 + rr)*HD + k8]) = v;
    }
}

// ============ persistent-weight 64-row GEMV: out = EPI(h @ B) ============
// SPLIT: B = BThi + BTlo (K doubled to 256). !SPLIT: single bf16 B (K=128).
template<int EPI, bool SPLIT>
__global__ __launch_bounds__(256) void gemv64_kernel(
        const float* __restrict__ A, const ushort* __restrict__ BThi,
        const ushort* __restrict__ BTlo, const float* __restrict__ bias,
        float* __restrict__ fdst, ushort* __restrict__ bdst, int mtiles) {
    constexpr int KW   = SPLIT ? 256 : 128;
    constexpr int BROW = 2 * KW;
    __shared__ ushort Bw[128 * KW];
    __shared__ ushort A_[64 * 128];
    char* Bwb = (char*)Bw;
    char* Ab  = (char*)A_;
    const int tid  = threadIdx.x;
    const int lane = tid & 63;
    const int wave = tid >> 6;
    const int l15  = lane & 15;
    const int kgrp = (lane >> 4) * 8;
    const int rbase = wave * 16;

    if (SPLIT) {
        #pragma unroll
        for (int p = 0; p < 16; ++p) {
            int idx = p * 256 + tid;
            int c = idx >> 5;
            int k8 = (idx & 31) * 8;
            const ushort* src = (k8 < 128) ? BThi : BTlo;
            u16x8 v = *reinterpret_cast<const u16x8*>(&src[(size_t)c*128 + (k8 & 127)]);
            *reinterpret_cast<u16x8*>(&Bwb[c*BROW + ((2*k8) ^ ((c & 7) << 4))]) = v;
        }
    } else {
        #pragma unroll
        for (int p = 0; p < 8; ++p) {
            int idx = p * 256 + tid;
            int c = idx >> 4;
            int k8 = (idx & 15) * 8;
            u16x8 v = *reinterpret_cast<const u16x8*>(&BThi[(size_t)c*128 + k8]);
            *reinterpret_cast<u16x8*>(&Bwb[c*BROW + ((2*k8) ^ ((c & 7) << 4))]) = v;
        }
    }
    float bt[8];
    if (EPI == 4) {
        #pragma unroll
        for (int cb = 0; cb < 8; ++cb) bt[cb] = bias[cb*16 + l15];
    }
    __syncthreads();

    for (int mt = blockIdx.x; mt < mtiles; mt += gridDim.x) {
        #pragma unroll
        for (int p = 0; p < 8; ++p) {
            int rr = p * 8 + (tid >> 5);
            int k4 = (tid & 31) * 4;
            f32x4 v = *reinterpret_cast<const f32x4*>(&A[(size_t)(mt*64 + rr)*HD + k4]);
            u16x4 b;
            b.x = f2bf(v.x); b.y = f2bf(v.y); b.z = f2bf(v.z); b.w = f2bf(v.w);
            *reinterpret_cast<u16x4*>(&Ab[rr*256 + ((2*k4) ^ ((rr & 7) << 4))]) = b;
        }
        __syncthreads();

        bf16x8 af[4];
        {
            int r = rbase + l15;
            #pragma unroll
            for (int q = 0; q < 4; ++q)
                af[q] = *reinterpret_cast<const bf16x8*>(&Ab[r*256 + ((2*(q*32 + kgrp)) ^ ((r & 7) << 4))]);
        }
        f32x4 acc[8];
        #pragma unroll
        for (int j = 0; j < 8; ++j) { acc[j].x=0.f; acc[j].y=0.f; acc[j].z=0.f; acc[j].w=0.f; }
        #pragma unroll
        for (int ks = 0; ks < (SPLIT ? 8 : 4); ++ks) {
            int kB = ks*32 + kgrp;
            #pragma unroll
            for (int cb = 0; cb < 8; ++cb) {
                int c = cb*16 + l15;
                bf16x8 bv = *reinterpret_cast<const bf16x8*>(&Bwb[c*BROW + ((2*kB) ^ ((c & 7) << 4))]);
                acc[cb] = __builtin_amdgcn_mfma_f32_16x16x32_bf16(af[ks & 3], bv, acc[cb], 0, 0, 0);
            }
        }

        #pragma unroll
        for (int cb = 0; cb < 8; ++cb) {
            int c = cb*16 + l15;
            #pragma unroll
            for (int i = 0; i < 4; ++i) {
                int row = mt*64 + rbase + (lane >> 4)*4 + i;
                size_t off = (size_t)row * HD + c;
                if (EPI == 4) fdst[off] = fmaxf(acc[cb][i] + bt[cb], 0.0f);
                else          bdst[off] = f2bf(acc[cb][i]);
            }
        }
        __syncthreads();
    }
}

// ======== persistent-weight fused node block (32-row tiles, 512 threads) ========
// GEMM1: t = ssp(aggb @ c2 + c2b)          [c2 single bf16, W1 32KB]
// GEMM2: hv = h + t @ (lwhi+lwlo) + lb -> h [lw split, W2 64KB]
// CHAIN: GEMM3: hxbn = bf16(hv @ c1n)       [c1n single bf16, W3 32KB]
// LDS: 32+64+32+8 = 136 KB -> 1 block/CU.
template<bool CHAIN>
__global__ __launch_bounds__(512, 1) void nodefused_kernel(
        const ushort* __restrict__ aggb,
        const ushort* __restrict__ c2T, const float* __restrict__ c2b,
        const ushort* __restrict__ lwhi, const ushort* __restrict__ lwlo,
        const float* __restrict__ lb,
        const ushort* __restrict__ c1nT,
        float* __restrict__ h, ushort* __restrict__ hxbn, int mtiles) {
    __shared__ ushort W1[128 * 128];   // 32KB c2 single
    __shared__ ushort W2[128 * 256];   // 64KB lw split
    __shared__ ushort W3[128 * 128];   // 32KB c1-next single
    __shared__ ushort BUF[32 * 128];   // 8KB (A, U, then hv)
    char* W1b = (char*)W1;
    char* W2b = (char*)W2;
    char* W3b = (char*)W3;
    char* Bu  = (char*)BUF;
    const int tid  = threadIdx.x;
    const int lane = tid & 63;
    const int wave = tid >> 6;
    const int l15  = lane & 15;
    const int kgrp = (lane >> 4) * 8;
    const int wr = (wave & 1) * 16;
    const int wc = (wave >> 1) * 2;

    // stage weights once
    #pragma unroll
    for (int p = 0; p < 4; ++p) {
        int idx = p * 512 + tid;           // 0..2047
        int c = idx >> 4;
        int k8 = (idx & 15) * 8;
        u16x8 v1 = *reinterpret_cast<const u16x8*>(&c2T[(size_t)c*128 + k8]);
        *reinterpret_cast<u16x8*>(&W1b[c*256 + ((2*k8) ^ ((c & 7) << 4))]) = v1;
        if (CHAIN) {
            u16x8 v3 = *reinterpret_cast<const u16x8*>(&c1nT[(size_t)c*128 + k8]);
            *reinterpret_cast<u16x8*>(&W3b[c*256 + ((2*k8) ^ ((c & 7) << 4))]) = v3;
        }
    }
    #pragma unroll
    for (int p = 0; p < 8; ++p) {
        int idx = p * 512 + tid;
        int c = idx >> 5;
        int k8 = (idx & 31) * 8;
        const ushort* s2 = (k8 < 128) ? lwhi : lwlo;
        u16x8 v2 = *reinterpret_cast<const u16x8*>(&s2[(size_t)c*128 + (k8 & 127)]);
        *reinterpret_cast<u16x8*>(&W2b[c*512 + ((2*k8) ^ ((c & 7) << 4))]) = v2;
    }
    float b1c[2], b2c[2];
    #pragma unroll
    for (int cb = 0; cb < 2; ++cb) {
        int c = (wc + cb)*16 + l15;
        b1c[cb] = c2b[c];
        b2c[cb] = lb[c];
    }
    __syncthreads();

    for (int mt = blockIdx.x; mt < mtiles; mt += gridDim.x) {
        // stage A = aggb tile; prefetch h
        {
            int rr = tid >> 4;
            int k8 = (tid & 15) * 8;
            u16x8 v = *reinterpret_cast<const u16x8*>(&aggb[(size_t)(mt*32 + rr)*HD + k8]);
            *reinterpret_cast<u16x8*>(&Bu[rr*256 + ((2*k8) ^ ((rr & 7) << 4))]) = v;
        }
        float hp[2][4];
        #pragma unroll
        for (int cb = 0; cb < 2; ++cb) {
            int c = (wc + cb)*16 + l15;
            #pragma unroll
            for (int i = 0; i < 4; ++i) {
                int row = mt*32 + wr + (lane >> 4)*4 + i;
                hp[cb][i] = h[(size_t)row * HD + c];
            }
        }
        __syncthreads();   // (1) A visible

        // ---- GEMM1: acc = A @ c2 (K=128 single) ----
        bf16x8 af[4];
        {
            int r = wr + l15;
            #pragma unroll
            for (int q = 0; q < 4; ++q)
                af[q] = *reinterpret_cast<const bf16x8*>(&Bu[r*256 + ((2*(q*32 + kgrp)) ^ ((r & 7) << 4))]);
        }
        f32x4 acc[2];
        #pragma unroll
        for (int j = 0; j < 2; ++j) { acc[j].x=0.f; acc[j].y=0.f; acc[j].z=0.f; acc[j].w=0.f; }
        #pragma unroll
        for (int ks = 0; ks < 4; ++ks) {
            int kB = ks*32 + kgrp;
            #pragma unroll
            for (int cb = 0; cb < 2; ++cb) {
                int c = (wc + cb)*16 + l15;
                bf16x8 bv = *reinterpret_cast<const bf16x8*>(&W1b[c*256 + ((2*kB) ^ ((c & 7) << 4))]);
                acc[cb] = __builtin_amdgcn_mfma_f32_16x16x32_bf16(af[ks], bv, acc[cb], 0, 0, 0);
            }
        }
        __syncthreads();   // (2) A reads done -> BUF reusable

        // epilogue1: ssp -> BUF (U role)
        #pragma unroll
        for (int cb = 0; cb < 2; ++cb) {
            int c = (wc + cb)*16 + l15;
            #pragma unroll
            for (int i = 0; i < 4; ++i) {
                int rrow = wr + (lane >> 4)*4 + i;
                ushort us = f2bf(ssp_f(acc[cb][i] + b1c[cb]));
                *reinterpret_cast<ushort*>(&Bu[rrow*256 + ((2*c) ^ ((rrow & 7) << 4))]) = us;
            }
        }
        __syncthreads();   // (3) U visible

        // ---- GEMM2: acc = U @ lw' (K=256 split) ----
        {
            int r = wr + l15;
            #pragma unroll
            for (int q = 0; q < 4; ++q)
                af[q] = *reinterpret_cast<const bf16x8*>(&Bu[r*256 + ((2*(q*32 + kgrp)) ^ ((r & 7) << 4))]);
        }
        #pragma unroll
        for (int j = 0; j < 2; ++j) { acc[j].x=0.f; acc[j].y=0.f; acc[j].z=0.f; acc[j].w=0.f; }
        #pragma unroll
        for (int ks = 0; ks < 8; ++ks) {
            int kB = ks*32 + kgrp;
            #pragma unroll
            for (int cb = 0; cb < 2; ++cb) {
                int c = (wc + cb)*16 + l15;
                bf16x8 bv = *reinterpret_cast<const bf16x8*>(&W2b[c*512 + ((2*kB) ^ ((c & 7) << 4))]);
                acc[cb] = __builtin_amdgcn_mfma_f32_16x16x32_bf16(af[ks & 3], bv, acc[cb], 0, 0, 0);
            }
        }
        // epilogue2: hv = h + acc + lb -> h (keep hv in regs)
        float hv[2][4];
        #pragma unroll
        for (int cb = 0; cb < 2; ++cb) {
            int c = (wc + cb)*16 + l15;
            #pragma unroll
            for (int i = 0; i < 4; ++i) {
                int row = mt*32 + wr + (lane >> 4)*4 + i;
                hv[cb][i] = hp[cb][i] + acc[cb][i] + b2c[cb];
                h[(size_t)row * HD + c] = hv[cb][i];
            }
        }
        __syncthreads();   // (4) GEMM2's U reads done -> BUF reusable

        if (CHAIN) {
            // stage bf16(hv) -> BUF
            #pragma unroll
            for (int cb = 0; cb < 2; ++cb) {
                int c = (wc + cb)*16 + l15;
                #pragma unroll
                for (int i = 0; i < 4; ++i) {
                    int rrow = wr + (lane >> 4)*4 + i;
                    *reinterpret_cast<ushort*>(&Bu[rrow*256 + ((2*c) ^ ((rrow & 7) << 4))]) = f2bf(hv[cb][i]);
                }
            }
            __syncthreads();   // (5) hv tile visible

            // ---- GEMM3: acc = hv @ c1n (K=128 single) ----
            {
                int r = wr + l15;
                #pragma unroll
                for (int q = 0; q < 4; ++q)
                    af[q] = *reinterpret_cast<const bf16x8*>(&Bu[r*256 + ((2*(q*32 + kgrp)) ^ ((r & 7) << 4))]);
            }
            #pragma unroll
            for (int j = 0; j < 2; ++j) { acc[j].x=0.f; acc[j].y=0.f; acc[j].z=0.f; acc[j].w=0.f; }
            #pragma unroll
            for (int ks = 0; ks < 4; ++ks) {
                int kB = ks*32 + kgrp;
                #pragma unroll
                for (int cb = 0; cb < 2; ++cb) {
                    int c = (wc + cb)*16 + l15;
                    bf16x8 bv = *reinterpret_cast<const bf16x8*>(&W3b[c*256 + ((2*kB) ^ ((c & 7) << 4))]);
                    acc[cb] = __builtin_amdgcn_mfma_f32_16x16x32_bf16(af[ks], bv, acc[cb], 0, 0, 0);
                }
            }
            // epilogue3: hxbn = bf16(acc)   (c1 has no bias)
            #pragma unroll
            for (int cb = 0; cb < 2; ++cb) {
                int c = (wc + cb)*16 + l15;
                #pragma unroll
                for (int i = 0; i < 4; ++i) {
                    int row = mt*32 + wr + (lane >> 4)*4 + i;
                    hxbn[(size_t)row * HD + c] = f2bf(acc[cb][i]);
                }
            }
            __syncthreads();   // (6) BUF reads done before next tile
        }
    }
}

// ========= fused gather-NN-segment-sum (16-slot unrolled, identity order) =========
__global__ __launch_bounds__(256) void gathersum_kernel(
        const ushort* __restrict__ Tb, const uint* __restrict__ meta,
        const int* __restrict__ rowp, const ushort* __restrict__ hxb,
        ushort* __restrict__ aggb, int N) {
    const int lane = threadIdx.x & 63;
    const int n = blockIdx.x * 4 + (threadIdx.x >> 6);
    if (n >= N) return;
    const int c0 = lane * 2;
    const int s0 = rowp[n], s1 = rowp[n + 1];
    float al[4] = {0.f, 0.f, 0.f, 0.f};
    float ah[4] = {0.f, 0.f, 0.f, 0.f};
    int s = s0;
    for (; s + 16 <= s1; s += 16) {
        uint m[16], tv[16], hv[16];
        #pragma unroll
        for (int k = 0; k < 16; ++k) m[k] = meta[s + k];
        #pragma unroll
        for (int k = 0; k < 16; ++k) {
            tv[k] = *reinterpret_cast<const uint*>(&Tb[(size_t)(m[k] >> 16) * HD + c0]);
            hv[k] = *reinterpret_cast<const uint*>(&hxb[(size_t)(m[k] & 0xFFFFu) * HD + c0]);
        }
        #pragma unroll
        for (int k = 0; k < 16; ++k) {
            al[k & 3] += __uint_as_float(tv[k] << 16) * __uint_as_float(hv[k] << 16);
            ah[k & 3] += __uint_as_float(tv[k] & 0xFFFF0000u) * __uint_as_float(hv[k] & 0xFFFF0000u);
        }
    }
    for (; s + 4 <= s1; s += 4) {
        uint m[4], tv[4], hv[4];
        #pragma unroll
        for (int k = 0; k < 4; ++k) m[k] = meta[s + k];
        #pragma unroll
        for (int k = 0; k < 4; ++k) {
            tv[k] = *reinterpret_cast<const uint*>(&Tb[(size_t)(m[k] >> 16) * HD + c0]);
            hv[k] = *reinterpret_cast<const uint*>(&hxb[(size_t)(m[k] & 0xFFFFu) * HD + c0]);
        }
        #pragma unroll
        for (int k = 0; k < 4; ++k) {
            al[k] += __uint_as_float(tv[k] << 16) * __uint_as_float(hv[k] << 16);
            ah[k] += __uint_as_float(tv[k] & 0xFFFF0000u) * __uint_as_float(hv[k] & 0xFFFF0000u);
        }
    }
    for (; s < s1; ++s) {
        uint m0 = meta[s];
        uint tv = *reinterpret_cast<const uint*>(&Tb[(size_t)(m0 >> 16) * HD + c0]);
        uint hv = *reinterpret_cast<const uint*>(&hxb[(size_t)(m0 & 0xFFFFu) * HD + c0]);
        al[0] += __uint_as_float(tv << 16) * __uint_as_float(hv << 16);
        ah[0] += __uint_as_float(tv & 0xFFFF0000u) * __uint_as_float(hv & 0xFFFF0000u);
    }
    float lo = (al[0] + al[1]) + (al[2] + al[3]);
    float hi = (ah[0] + ah[1]) + (ah[2] + ah[3]);
    uint out = ((uint)f2bf(lo)) | (((uint)f2bf(hi)) << 16);
    *reinterpret_cast<uint*>(&aggb[(size_t)n * HD + c0]) = out;
}

// ================= mean pool =================
__global__ void pool_kernel(const float* __restrict__ h1, const int* __restrict__ batch,
                            float* __restrict__ gsum, float* __restrict__ gcnt, int N) {
    __shared__ float pool[NGRAPH][HD];
    __shared__ float cnt[NGRAPH];
    const int t = threadIdx.x;
    #pragma unroll
    for (int g = 0; g < NGRAPH; ++g) pool[g][t] = 0.0f;
    if (t < NGRAPH) cnt[t] = 0.0f;
    __syncthreads();
    int chunk = (N + gridDim.x - 1) / gridDim.x;
    int n0 = blockIdx.x * chunk, n1 = min(N, n0 + chunk);
    for (int n = n0; n < n1; ++n) {
        int b = batch[n];
        pool[b][t] += h1[(size_t)n * HD + t];
        if (t == 0) cnt[b] += 1.0f;
    }
    __syncthreads();
    #pragma unroll
    for (int g = 0; g < NGRAPH; ++g) atomicAdd(&gsum[g*HD + t], pool[g][t]);
    if (t < NGRAPH) atomicAdd(&gcnt[t], cnt[t]);
}

// ================= head =================
__global__ void finalize_kernel(const float* __restrict__ gsum, const float* __restrict__ gcnt,
                                const float* __restrict__ l1w, const float* __restrict__ l1b,
                                const float* __restrict__ l2w, const float* __restrict__ l2b,
                                float* __restrict__ d_out) {
    __shared__ float ge[HD];
    __shared__ float h2[HD];
    const int g = blockIdx.x, t = threadIdx.x;
    float cnt = fmaxf(gcnt[g], 1.0f);
    float v = gsum[g*HD + t] / cnt;
    d_out[g*HD + t] = v;
    ge[t] = v;
    __syncthreads();
    float acc = l1b[t];
    #pragma unroll 8
    for (int k = 0; k < HD; ++k) acc += ge[k] * l1w[k*HD + t];
    h2[t] = fmaxf(acc, 0.0f);
    __syncthreads();
    if (t < NCLS) {
        float o = l2b[t];
        #pragma unroll 8
        for (int k = 0; k < HD; ++k) o += h2[k] * l2w[k*NCLS + t];
        d_out[NGRAPH*HD + g*NCLS + t] = o;
    }
}

extern "C" void kernel_launch(void* const* d_in, const int* in_sizes, int n_in,
                              void* d_out, int out_size, void* d_ws, size_t ws_size,
                              hipStream_t stream) {
    const float* x     = (const float*)d_in[0];
    const float* pos   = (const float*)d_in[1];
    const int*   eidx  = (const int*)d_in[2];
    const int*   batch = (const int*)d_in[3];
    const float* emb_w = (const float*)d_in[4];
    const float* emb_b = (const float*)d_in[5];
    const float* m1w   = (const float*)d_in[6];
    const float* m1b   = (const float*)d_in[7];
    const float* m2w   = (const float*)d_in[8];
    const float* m2b   = (const float*)d_in[9];
    const float* c1w   = (const float*)d_in[10];
    const float* c2w   = (const float*)d_in[11];
    const float* c2b   = (const float*)d_in[12];
    const float* lw    = (const float*)d_in[13];
    const float* lb    = (const float*)d_in[14];
    const float* l1w   = (const float*)d_in[15];
    const float* l1b   = (const float*)d_in[16];
    const float* l2w   = (const float*)d_in[17];
    const float* l2b   = (const float*)d_in[18];

    const int N = in_sizes[0] / 21;          // 20000
    const int E = in_sizes[2] / 2;           // 640000
    const int* row = eidx;
    const int* col = eidx + E;
    const int NT64 = (N + 63) / 64;          // 313
    const int NT32 = (N + 31) / 32;          // 625
    const int NB   = (N + 255) / 256;        // 79
    const int Npad = NT64 * 64 + 64;

    size_t off = 0;
    char* base = (char*)d_ws;
    auto alloc = [&](size_t bytes) -> void* {
        off = (off + 255) & ~(size_t)255;
        void* p = base + off;
        off += bytes;
        return p;
    };
    int*    deg     = (int*)alloc((size_t)N * 4);
    int*    cursor  = (int*)alloc((size_t)N * 4);
    int*    rowp    = (int*)alloc((size_t)(N + 1) * 4);
    int*    bsum    = (int*)alloc(512 * 4);
    int*    boff    = (int*)alloc(512 * 4);
    uint*   meta    = (uint*)alloc((size_t)E * 4);
    float*  h       = (float*)alloc((size_t)Npad * HD * 4);
    ushort* hxb     = (ushort*)alloc((size_t)Npad * HD * 2);
    ushort* aggb    = (ushort*)alloc((size_t)Npad * HD * 2);
    float*  h1      = (float*)alloc((size_t)Npad * HD * 4);
    ushort* Tb6     = (ushort*)alloc((size_t)6 * NTAB2 * HD * 2);
    ushort* m1T     = (ushort*)alloc((size_t)6 * 128 * 64 * 2);
    ushort* nodeThi = (ushort*)alloc((size_t)19 * 128 * 128 * 2);
    ushort* nodeTlo = (ushort*)alloc((size_t)19 * 128 * 128 * 2);
    ushort* m2T     = (ushort*)alloc((size_t)6 * 128 * 128 * 2);
    float*  gsum    = (float*)alloc((size_t)NGRAPH * HD * 4);
    float*  gcnt    = (float*)alloc((size_t)NGRAPH * 4);

    // ---- one-time: weight prep + CSR + filter tables ----
    prep_kernel<<<1792, 256, 0, stream>>>(m1w, c1w, c2w, lw, l1w, m2w,
                                          m1T, nodeThi, nodeTlo, m2T);
    hipMemsetAsync(deg, 0, (size_t)N * 4, stream);
    hist_kernel<<<(E + 255)/256, 256, 0, stream>>>(col, deg, E);
    scan1_kernel<<<NB, 256, 0, stream>>>(deg, rowp, bsum, N);
    scan2_kernel<<<1, 256, 0, stream>>>(bsum, boff, NB, rowp + N);
    scan3_kernel<<<NB, 256, 0, stream>>>(rowp, boff, cursor, N);
    fill_kernel<<<(E + 255)/256, 256, 0, stream>>>(row, col, pos, cursor, meta, E);
    buildtab_kernel<<<6 * (NTAB2/128), 256, 0, stream>>>(m1T, m2T, m1b, m2b, Tb6);
    embed_kernel<<<(N*HD + 255)/256, 256, 0, stream>>>(x, emb_w, emb_b, h, N);

    // hxb for layer 0 (single-bf16 c1)
    gemv64_kernel<5, false><<<NT64, 256, 0, stream>>>(h, nodeThi, nullptr, nullptr,
                                                      nullptr, hxb, NT64);

    for (int l = 0; l < NLAYER; ++l) {
        const ushort* c2T  = nodeThi + (size_t)(6 + l) * 16384;   // single bf16
        const ushort* lThi = nodeThi + (size_t)(12 + l) * 16384;
        const ushort* lTlo = nodeTlo + (size_t)(12 + l) * 16384;

        gathersum_kernel<<<(N + 3)/4, 256, 0, stream>>>(
            Tb6 + (size_t)l * NTAB2 * HD, meta, rowp, hxb, aggb, N);

        if (l < NLAYER - 1) {
            const ushort* c1nT = nodeThi + (size_t)(l + 1) * 16384;
            nodefused_kernel<true><<<256, 512, 0, stream>>>(
                aggb, c2T, c2b + l*HD, lThi, lTlo, lb + l*HD, c1nT, h, hxb, NT32);
        } else {
            nodefused_kernel<false><<<256, 512, 0, stream>>>(
                aggb, c2T, c2b + l*HD, lThi, lTlo, lb + l*HD, nullptr, h, nullptr, NT32);
            // head: h1 = relu(h @ lin1 + b1)  (split, bit-identical path)
            gemv64_kernel<4, true><<<NT64, 256, 0, stream>>>(
                h, nodeThi + (size_t)18 * 16384, nodeTlo + (size_t)18 * 16384,
                l1b, h1, nullptr, NT64);
        }
    }

    hipMemsetAsync(gsum, 0, (size_t)(NGRAPH*HD + NGRAPH) * 4, stream);
    pool_kernel<<<256, HD, 0, stream>>>(h1, batch, gsum, gcnt, N);
    finalize_kernel<<<NGRAPH, HD, 0, stream>>>(gsum, gcnt, l1w, l1b, l2w, l2b,
                                               (float*)d_out);
}